// Round 21
// baseline (26981.293 us; speedup 1.0000x reference)
//
#include <hip/hip_runtime.h>
#include <stdint.h>
#include <math.h>

#define TSTEPS 256
#define BATCH  256
#define OBS_D  512
#define FEATD  512
#define NACT   15
#define HDIM   528
#define HB     (HDIM*BATCH)
#define PK     544              /* padded K per half (528 + 16 zeros) */

typedef __attribute__((ext_vector_type(8))) short short8v;
typedef __attribute__((ext_vector_type(4))) short short4v;
typedef __attribute__((ext_vector_type(4))) float float4v;

/* ---- ws BYTE offsets (base layout 5,296,128 B; optional wpre region after) ---- */
#define OFF_ND_B     0
#define OFF_FLAG_B   262144
#define OFF_ALW_B    262208
#define XP_B         315392
#define SLOT_B       557056
#define PL_B         278528
#define H0P_B        1986560
#define H1P_B        3100672
#define C0_B         4214784
#define C1_B         4755456
#define WS_END_B     5296128
/* wpre: [layer][plane hi/lo][2112 rows][1088 k] bf16.
   plane = 2,297,856 shorts; layer = 4,595,712 shorts = 9,191,424 B; total 18,382,848 B */
#define WPRE_B       WS_END_B
#define PSTR_S       2297856UL          /* plane stride, shorts */
#define LSTR_S       4595712UL          /* layer stride, shorts */
#define NEED_FAST_B  (WPRE_B + 18382848ULL)   /* 23,678,976 */

/* ALW float offsets */
#define DBS0   0
#define DBS1   2112
#define DBENC  4224
#define DHW    4736
#define DHB    13184
#define DALW_N 13200

/* out float offsets */
#define OUT_POL   0
#define OUT_BASE  983040
#define OUT_ACT   1048576
#define OUT_H     1114112
#define OUT_C     1384448

__device__ __forceinline__ float sigf_(float x){ return 1.0f/(1.0f+expf(-x)); }

__device__ __forceinline__ unsigned short f2bf(float f){
  unsigned u = __float_as_uint(f);
  unsigned r = (u + 0x7FFFu + ((u>>16)&1u)) >> 16;
  return (unsigned short)r;
}
__device__ __forceinline__ float bf2f(unsigned short s){
  return __uint_as_float(((unsigned)s)<<16);
}

__device__ __forceinline__ uint32_t rotl32_(uint32_t x, uint32_t d){
  return (x<<d)|(x>>(32u-d));
}

/* JAX partitionable threefry 32-bit: bits = out0 ^ out1. [VERIFIED R5-R20] */
__device__ double gumbel_for(uint32_t idx){
  uint32_t x0 = 0u, x1 = idx;
  const uint32_t k0 = 0u, k1 = 1u;
  const uint32_t ks[3] = {k0, k1, 0x1BD11BDAu ^ k0 ^ k1};
  x0 += ks[0]; x1 += ks[1];
  const uint32_t R0[4] = {13u,15u,26u,6u}, R1[4] = {17u,29u,16u,24u};
  #pragma unroll
  for (int g=0; g<5; ++g){
    const uint32_t* r = (g&1) ? R1 : R0;
    #pragma unroll
    for (int j=0;j<4;++j){ x0 += x1; x1 = rotl32_(x1, r[j]); x1 ^= x0; }
    x0 += ks[(g+1)%3];
    x1 += ks[(g+2)%3] + (uint32_t)(g+1);
  }
  const uint32_t bits = x0 ^ x1;
  float u = __uint_as_float((bits>>9) | 0x3f800000u) - 1.0f;
  const float TINY = 1.17549435e-38f;
  u = u * (1.0f - TINY) + TINY;
  u = fmaxf(TINY, u);
  return -log(-log((double)u));
}

__global__ void zero_kernel(float* __restrict__ p, int n){
  int i = blockIdx.x*256 + threadIdx.x;
  if (i < n) p[i] = 0.0f;
}

__global__ void detect_term_kernel(const void* __restrict__ term, int* __restrict__ flag){
  __shared__ int s_nf, s_nb, s_ni;
  if (threadIdx.x==0){ s_nf=0; s_nb=0; s_ni=0; }
  __syncthreads();
  const uint8_t*  pb = (const uint8_t*)term;
  const uint32_t* pw = (const uint32_t*)term;
  int nf=0, nb=0, ni=0;
  for (int i=threadIdx.x; i<16384; i+=256){
    uint32_t v = pw[i];
    if (v == 0x3F800000u) nf++;
    if (v == 1u) ni++;
  }
  for (int o=threadIdx.x; o<65536; o+=256){
    if ((o&3) && pb[o]) nb++;
  }
  if (nf) atomicAdd(&s_nf, nf);
  if (nb) atomicAdd(&s_nb, nb);
  if (ni) atomicAdd(&s_ni, ni);
  __syncthreads();
  if (threadIdx.x==0){
    flag[0] = (s_nf>0) ? 2 : ((s_nb>0) ? 0 : ((s_ni>0) ? 1 : 0));
  }
}

__global__ void nd_kernel(const void* __restrict__ term, const int* __restrict__ flag,
                          float* __restrict__ nd){
  int i = blockIdx.x*256 + threadIdx.x;
  if (i >= TSTEPS*BATCH) return;
  int f = flag[0];
  bool done;
  if (f == 0)      done = ((const uint8_t*)term)[i] != 0;
  else if (f == 1) done = ((const int*)term)[i] != 0;
  else             done = ((const float*)term)[i] != 0.0f;
  nd[i] = done ? 0.0f : 1.0f;
}

__global__ void prep_small_kernel(float* __restrict__ alw,
    const float* __restrict__ bih0, const float* __restrict__ bhh0,
    const float* __restrict__ bih1, const float* __restrict__ bhh1,
    const float* __restrict__ benc,
    const float* __restrict__ Wpol, const float* __restrict__ bpol,
    const float* __restrict__ Wbase, const float* __restrict__ bbase){
  int i = blockIdx.x*256 + threadIdx.x;
  if (i >= DALW_N) return;
  if (i < 2112)            alw[DBS0 + i] = bih0[i] + bhh0[i];
  else if (i < 4224)       { int j=i-2112; alw[DBS1 + j] = bih1[j] + bhh1[j]; }
  else if (i < 4736)       { int j=i-4224; alw[DBENC + j] = benc[j]; }
  else if (i < 13184)      { int j=i-4736; int r=j/HDIM, k=j%HDIM;
                             alw[DHW + j] = (r<NACT ? Wpol[r*HDIM+k] : Wbase[k]); }
  else                     { int j=i-13184; alw[DHB + j] = (j<NACT ? bpol[j] : bbase[0]); }
}

/* One-time weight conversion into ROW-MAJOR bf16 hi/lo mirror of the virtual
   matrix: row = gate*528+j (0..2112), virtual k = [wih 528 | 0 x16 | whh 528 | 0 x16].
   thread = (layer, row, 16-k chunk). Trivial layout: wpre[layer][plane][row][k]. */
__global__ void prep_w_kernel(
    const float* __restrict__ wih0, const float* __restrict__ whh0,
    const float* __restrict__ wih1, const float* __restrict__ whh1,
    unsigned short* __restrict__ wpre)
{
  int idx = blockIdx.x*256 + threadIdx.x;
  if (idx >= 287232) return;            /* 2 * 2112 * 68 */
  const int kc    = idx % 68;
  const int row   = (idx / 68) % 2112;
  const int layer = idx / (68*2112);
  const float* wih = layer ? wih1 : wih0;
  const float* whh = layer ? whh1 : whh0;
  const int vk0 = kc*16;
  float v[16];
  if (vk0 < 528){
    const float4* p = (const float4*)(wih + (size_t)row*HDIM + vk0);
    #pragma unroll
    for (int q=0;q<4;++q){ float4 x = p[q]; v[q*4]=x.x; v[q*4+1]=x.y; v[q*4+2]=x.z; v[q*4+3]=x.w; }
  } else if (vk0 < 544){
    #pragma unroll
    for (int i=0;i<16;++i) v[i]=0.0f;
  } else if (vk0 < 1072){
    const float4* p = (const float4*)(whh + (size_t)row*HDIM + (vk0-544));
    #pragma unroll
    for (int q=0;q<4;++q){ float4 x = p[q]; v[q*4]=x.x; v[q*4+1]=x.y; v[q*4+2]=x.z; v[q*4+3]=x.w; }
  } else {
    #pragma unroll
    for (int i=0;i<16;++i) v[i]=0.0f;
  }
  short8v h0v, h1v, l0v, l1v;
  #pragma unroll
  for (int i=0;i<8;++i){
    unsigned short hb = f2bf(v[i]);
    h0v[i]=(short)hb; l0v[i]=(short)f2bf(v[i]-bf2f(hb));
  }
  #pragma unroll
  for (int i=0;i<8;++i){
    unsigned short hb = f2bf(v[8+i]);
    h1v[i]=(short)hb; l1v[i]=(short)f2bf(v[8+i]-bf2f(hb));
  }
  unsigned short* hi = wpre + (size_t)layer*LSTR_S + (size_t)row*1088 + vk0;
  unsigned short* lo = hi + PSTR_S;
  *(short8v*)(hi)     = h0v;
  *(short8v*)(hi + 8) = h1v;
  *(short8v*)(lo)     = l0v;
  *(short8v*)(lo + 8) = l1v;
}

/* ---------- shared LSTM epilogue: gate exchange + cell update (verified R19) ---------- */
__device__ __forceinline__ void lstm_epilogue(
    float* __restrict__ gf, float4v* acc, int j0, int n0, int step,
    const float* __restrict__ bsum, const float* __restrict__ nd,
    float* __restrict__ cbuf, unsigned short* __restrict__ oHh,
    unsigned short* __restrict__ oHl, int tid)
{
  const int w = tid>>6, l = tid&63;
  #pragma unroll
  for (int s=0;s<4;++s){
    #pragma unroll
    for (int r2=0;r2<4;++r2)
      gf[w*1088 + (((l>>4)<<2)+r2)*68 + s*16 + (l&15)] = acc[s][r2];
  }
  __syncthreads();
  const int bl = tid&63, j4 = tid>>6;
  const int b = n0 + bl;
  const float ndv = nd[step*BATCH + b];
  short4v hv, lv;
  #pragma unroll
  for (int jj=0;jj<4;++jj){
    const int jloc = j4*4 + jj, j = j0 + jloc;
    const float gi = gf[0*1088 + jloc*68 + bl] + bsum[j];
    const float gff= gf[1*1088 + jloc*68 + bl] + bsum[528 + j];
    const float gg = gf[2*1088 + jloc*68 + bl] + bsum[1056 + j];
    const float go = gf[3*1088 + jloc*68 + bl] + bsum[1584 + j];
    const int idx = j*BATCH + b;
    const float cold = cbuf[idx]*ndv;
    const float cn = sigf_(gff)*cold + sigf_(gi)*tanhf(gg);
    const float hn = sigf_(go)*tanhf(cn);
    cbuf[idx] = cn;
    const unsigned short hb = f2bf(hn);
    hv[jj] = (short)hb;
    lv[jj] = (short)f2bf(hn - bf2f(hb));
  }
  *(short4v*)(oHh + (size_t)b*PK + j0 + j4*4) = hv;
  *(short4v*)(oHl + (size_t)b*PK + j0 + j4*4) = lv;
}

/* ---------- SLOW (fallback) LSTM: per-step staging, verified R19 ---------- */
__device__ __forceinline__ void lstm_mfma_slow(
    unsigned short* __restrict__ smem_u,
    int j16, int nb, int step,
    const unsigned short* __restrict__ bAh, const unsigned short* __restrict__ bAl,
    const unsigned short* __restrict__ bBh, const unsigned short* __restrict__ bBl,
    unsigned short* __restrict__ oHh, unsigned short* __restrict__ oHl,
    const float* __restrict__ wih, const float* __restrict__ whh,
    const float* __restrict__ bsum, const float* __restrict__ nd,
    float* __restrict__ cbuf, int tid)
{
  const int w = tid>>6, l = tid&63;
  const int j0 = j16*16, n0 = nb*64;
  const int sr = tid&63, kq = tid>>6;
  const int gate = sr>>4, jr = j0 + (sr&15);
  const float* rih = wih + (size_t)(gate*528 + jr)*528;
  const float* rhh = whh + (size_t)(gate*528 + jr)*528;
  const short8v zv = {0,0,0,0,0,0,0,0};

  bool ndm[4];
  #pragma unroll
  for (int s=0;s<4;++s) ndm[s] = nd[step*BATCH + n0 + s*16 + (l&15)] != 0.0f;

  float4v acc[4];
  #pragma unroll
  for (int s=0;s<4;++s) acc[s] = (float4v){0.f,0.f,0.f,0.f};

  auto STAGE = [&](int cc, int bsel){
    const int vk0 = cc*64 + kq*16;
    float v[16];
    if (vk0 < 528){
      const float4* p = (const float4*)(rih + vk0);
      #pragma unroll
      for (int q=0;q<4;++q){ float4 x = p[q]; v[q*4]=x.x; v[q*4+1]=x.y; v[q*4+2]=x.z; v[q*4+3]=x.w; }
    } else if (vk0 < 544){
      #pragma unroll
      for (int i=0;i<16;++i) v[i]=0.0f;
    } else if (vk0 < 1072){
      const float4* p = (const float4*)(rhh + (vk0-544));
      #pragma unroll
      for (int q=0;q<4;++q){ float4 x = p[q]; v[q*4]=x.x; v[q*4+1]=x.y; v[q*4+2]=x.z; v[q*4+3]=x.w; }
    } else {
      #pragma unroll
      for (int i=0;i<16;++i) v[i]=0.0f;
    }
    short8v hA, hB, lA, lB;
    #pragma unroll
    for (int i=0;i<8;++i){
      unsigned short hb = f2bf(v[i]);
      hA[i] = (short)hb; lA[i] = (short)f2bf(v[i] - bf2f(hb));
    }
    #pragma unroll
    for (int i=0;i<8;++i){
      unsigned short hb = f2bf(v[8+i]);
      hB[i] = (short)hb; lB[i] = (short)f2bf(v[8+i] - bf2f(hb));
    }
    unsigned short* dh = smem_u + bsel*9216 + sr*72 + kq*16;
    *(short8v*)(dh)          = hA;
    *(short8v*)(dh + 8)      = hB;
    *(short8v*)(dh + 4608)   = lA;
    *(short8v*)(dh + 4616)   = lB;
  };

  auto KSTEP = [&](int ks){
    const unsigned short* sl = smem_u + ((ks>>1)&1)*9216;
    const int aoff = (16*w + (l&15))*72 + (ks&1)*32 + ((l>>4)<<3);
    const short8v ah = *(const short8v*)(sl + aoff);
    const short8v al = *(const short8v*)(sl + 4608 + aoff);
    const bool second = (ks >= 17);
    const int kin = (second ? (ks-17)*32 : ks*32) + ((l>>4)<<3);
    const unsigned short* ph  = second ? bBh : bAh;
    const unsigned short* pl2 = second ? bBl : bAl;
    #pragma unroll
    for (int s=0;s<4;++s){
      const int n = n0 + s*16 + (l&15);
      short8v bh = *(const short8v*)(ph  + (size_t)n*PK + kin);
      short8v bl = *(const short8v*)(pl2 + (size_t)n*PK + kin);
      if (second && !ndm[s]){ bh = zv; bl = zv; }
      acc[s] = __builtin_amdgcn_mfma_f32_16x16x32_bf16(ah, bh, acc[s], 0,0,0);
      acc[s] = __builtin_amdgcn_mfma_f32_16x16x32_bf16(ah, bl, acc[s], 0,0,0);
      acc[s] = __builtin_amdgcn_mfma_f32_16x16x32_bf16(al, bh, acc[s], 0,0,0);
    }
  };

  STAGE(0, 0);
  __syncthreads();
  #pragma unroll 1
  for (int cc=0; cc<17; ++cc){
    if (cc < 16) STAGE(cc+1, (cc+1)&1);
    KSTEP(2*cc); KSTEP(2*cc+1);
    __syncthreads();
  }
  lstm_epilogue((float*)smem_u, acc, j0, n0, step, bsum, nd, cbuf, oHh, oHl, tid);
}

/* ---------- FAST LSTM: A-fragments read directly from row-major bf16 mirror.
   Same MFMA order as slow (ks 0..33) -> bitwise-identical results. ---------- */
__device__ __forceinline__ void lstm_mfma_fast(
    float* __restrict__ gf,
    int j16, int nb, int step,
    const unsigned short* __restrict__ wpreL,  /* layer base (hi); lo = +PSTR_S */
    const unsigned short* __restrict__ bAh, const unsigned short* __restrict__ bAl,
    const unsigned short* __restrict__ bBh, const unsigned short* __restrict__ bBl,
    unsigned short* __restrict__ oHh, unsigned short* __restrict__ oHl,
    const float* __restrict__ bsum, const float* __restrict__ nd,
    float* __restrict__ cbuf, int tid)
{
  const int w = tid>>6, l = tid&63;
  const int j0 = j16*16, n0 = nb*64;
  const short8v zv = {0,0,0,0,0,0,0,0};

  bool ndm[4];
  #pragma unroll
  for (int s=0;s<4;++s) ndm[s] = nd[step*BATCH + n0 + s*16 + (l&15)] != 0.0f;

  float4v acc[4];
  #pragma unroll
  for (int s=0;s<4;++s) acc[s] = (float4v){0.f,0.f,0.f,0.f};

  const unsigned short* aH = wpreL + (size_t)(w*528 + j0 + (l&15))*1088;
  const unsigned short* aL = aH + PSTR_S;
  const int koff = (l>>4)<<3;

  /* first half: ks 0..16, B = x (or h0) planes, no mask */
  #pragma unroll 2
  for (int ks=0; ks<17; ++ks){
    const int ka = ks*32 + koff;
    const short8v ah = *(const short8v*)(aH + ka);
    const short8v al = *(const short8v*)(aL + ka);
    #pragma unroll
    for (int s=0;s<4;++s){
      const int n = n0 + s*16 + (l&15);
      const short8v bh = *(const short8v*)(bAh + (size_t)n*PK + ka);
      const short8v bl = *(const short8v*)(bAl + (size_t)n*PK + ka);
      acc[s] = __builtin_amdgcn_mfma_f32_16x16x32_bf16(ah, bh, acc[s], 0,0,0);
      acc[s] = __builtin_amdgcn_mfma_f32_16x16x32_bf16(ah, bl, acc[s], 0,0,0);
      acc[s] = __builtin_amdgcn_mfma_f32_16x16x32_bf16(al, bh, acc[s], 0,0,0);
    }
  }
  /* second half: ks 17..33, B = recurrent h planes, masked by nd */
  #pragma unroll 2
  for (int ks=17; ks<34; ++ks){
    const int ka = ks*32 + koff;
    const int kin = ka - 544;
    const short8v ah = *(const short8v*)(aH + ka);
    const short8v al = *(const short8v*)(aL + ka);
    #pragma unroll
    for (int s=0;s<4;++s){
      const int n = n0 + s*16 + (l&15);
      short8v bh = *(const short8v*)(bBh + (size_t)n*PK + kin);
      short8v bl = *(const short8v*)(bBl + (size_t)n*PK + kin);
      if (!ndm[s]){ bh = zv; bl = zv; }
      acc[s] = __builtin_amdgcn_mfma_f32_16x16x32_bf16(ah, bh, acc[s], 0,0,0);
      acc[s] = __builtin_amdgcn_mfma_f32_16x16x32_bf16(ah, bl, acc[s], 0,0,0);
      acc[s] = __builtin_amdgcn_mfma_f32_16x16x32_bf16(al, bh, acc[s], 0,0,0);
    }
  }
  lstm_epilogue(gf, acc, j0, n0, step, bsum, nd, cbuf, oHh, oHl, tid);
}

/* ---------- encoder / extras / head common bodies (verified R19) ---------- */
__device__ __forceinline__ void enc_body(float* __restrict__ smemf,
    const float* __restrict__ obs, const float* __restrict__ wenc,
    const float* __restrict__ alw, char* wsc, int te, int e, int tid)
{
  unsigned short* xh = (unsigned short*)(wsc + XP_B + (te%3)*SLOT_B);
  unsigned short* xl = (unsigned short*)(wsc + XP_B + (te%3)*SLOT_B + PL_B);
  float (*lx)[257] = (float(*)[257])smemf;
  const int f0 = e*8;
  const int b = tid;
  float acc[8];
  const float* wrow[8];
  #pragma unroll
  for (int c=0;c<8;++c){ acc[c]=alw[DBENC+f0+c]; wrow[c]=wenc+(size_t)(f0+c)*OBS_D; }
  const int r0 = tid>>3;
  const int kk = (tid&7)<<2;
  for (int kc=0; kc<OBS_D; kc+=32){
    __syncthreads();
    #pragma unroll
    for (int rr2=0; rr2<256; rr2+=32){
      const float4 v = *(const float4*)(obs + ((size_t)te*BATCH + (r0+rr2))*OBS_D + kc + kk);
      lx[kk+0][r0+rr2]=v.x; lx[kk+1][r0+rr2]=v.y; lx[kk+2][r0+rr2]=v.z; lx[kk+3][r0+rr2]=v.w;
    }
    __syncthreads();
    #pragma unroll 4
    for (int k2=0;k2<32;++k2){
      const float xv = lx[k2][b];
      #pragma unroll
      for (int c=0;c<8;++c) acc[c] = fmaf(xv, wrow[c][kc+k2], acc[c]);
    }
  }
  short8v hv, lv;
  #pragma unroll
  for (int c=0;c<8;++c){
    const float v = fmaxf(acc[c], 0.0f);
    const unsigned short hb = f2bf(v);
    hv[c] = (short)hb; lv[c] = (short)f2bf(v - bf2f(hb));
  }
  *(short8v*)(xh + (size_t)b*PK + f0) = hv;
  *(short8v*)(xl + (size_t)b*PK + f0) = lv;
}

__device__ __forceinline__ void extras_body(char* wsc,
    const float* __restrict__ reward, const int* __restrict__ lastAct, int te, int tid)
{
  unsigned short* xh = (unsigned short*)(wsc + XP_B + (te%3)*SLOT_B);
  unsigned short* xl = (unsigned short*)(wsc + XP_B + (te%3)*SLOT_B + PL_B);
  const int b = tid;
  float vals[16];
  const float r = reward[te*BATCH + b];
  vals[0] = fminf(fmaxf(r, -1.0f), 1.0f);
  const int la = lastAct[te*BATCH + b];
  #pragma unroll
  for (int a2=0; a2<NACT; ++a2) vals[1+a2] = (a2==la) ? 1.0f : 0.0f;
  short8v hv0, lv0, hv1, lv1;
  #pragma unroll
  for (int i=0;i<8;++i){
    unsigned short hb = f2bf(vals[i]);
    hv0[i]=(short)hb; lv0[i]=(short)f2bf(vals[i]-bf2f(hb));
  }
  #pragma unroll
  for (int i=0;i<8;++i){
    unsigned short hb = f2bf(vals[8+i]);
    hv1[i]=(short)hb; lv1[i]=(short)f2bf(vals[8+i]-bf2f(hb));
  }
  *(short8v*)(xh + (size_t)b*PK + 512) = hv0;
  *(short8v*)(xh + (size_t)b*PK + 520) = hv1;
  *(short8v*)(xl + (size_t)b*PK + 512) = lv0;
  *(short8v*)(xl + (size_t)b*PK + 520) = lv1;
}

__device__ __forceinline__ void head_body(char* wsc, const float* __restrict__ alw,
    float* __restrict__ out, int s, int tid)
{
  const int pa = s&1;
  const unsigned short* hh = (const unsigned short*)(wsc + H1P_B + pa*SLOT_B);
  const unsigned short* hl = (const unsigned short*)(wsc + H1P_B + pa*SLOT_B + PL_B);
  const int b = tid;
  float acc[16];
  #pragma unroll
  for (int c=0;c<16;++c) acc[c]=alw[DHB+c];
  for (int kc=0; kc<66; ++kc){
    const short8v H = *(const short8v*)(hh + (size_t)b*PK + kc*8);
    const short8v L = *(const short8v*)(hl + (size_t)b*PK + kc*8);
    #pragma unroll
    for (int u=0;u<8;++u){
      const float hv = bf2f((unsigned short)H[u]) + bf2f((unsigned short)L[u]);
      const int k = kc*8+u;
      #pragma unroll
      for (int c=0;c<16;++c) acc[c] = fmaf(hv, alw[DHW + (size_t)c*HDIM + k], acc[c]);
    }
  }
  const int row = s*BATCH + b;
  #pragma unroll
  for (int c=0;c<15;++c) out[OUT_POL + (size_t)row*NACT + c] = acc[c];
  out[OUT_BASE + row] = acc[15];
  double best = -1.0e300; int bi = 0;
  #pragma unroll
  for (int a2=0; a2<NACT; ++a2){
    const double v = (double)acc[a2] + gumbel_for((uint32_t)(row*NACT + a2));
    if (v > best){ best = v; bi = a2; }
  }
  out[OUT_ACT + row] = (float)bi;
}

/* ---------- role dispatch helper ---------- */
struct LstmCtx {
  const unsigned short *bAh,*bAl,*bBh,*bBl; unsigned short *oHh,*oHl;
  const float *wih,*whh,*bsum; float* cbuf; int layer, j16, nb, step;
};
__device__ __forceinline__ bool lstm_ctx(char* wsc, float* alw, int bid, int t,
    const float* wih0, const float* whh0, const float* wih1, const float* whh1,
    LstmCtx& cx)
{
  const int layer = (bid < 132) ? 0 : 1;
  const int rr = layer ? bid-132 : bid;
  const int step = layer ? t-1 : t;
  if (step < 0 || step > 255) return false;
  cx.layer = layer; cx.step = step; cx.j16 = rr>>2; cx.nb = rr&3;
  if (layer == 0){
    const int sl = step%3, pp = (step+1)&1, po = step&1;
    cx.bAh = (const unsigned short*)(wsc + XP_B + sl*SLOT_B);
    cx.bAl = (const unsigned short*)(wsc + XP_B + sl*SLOT_B + PL_B);
    cx.bBh = (const unsigned short*)(wsc + H0P_B + pp*SLOT_B);
    cx.bBl = (const unsigned short*)(wsc + H0P_B + pp*SLOT_B + PL_B);
    cx.oHh = (unsigned short*)(wsc + H0P_B + po*SLOT_B);
    cx.oHl = (unsigned short*)(wsc + H0P_B + po*SLOT_B + PL_B);
    cx.wih = wih0; cx.whh = whh0; cx.bsum = alw + DBS0;
    cx.cbuf = (float*)(wsc + C0_B);
  } else {
    const int pa = step&1, pb2 = (step+1)&1;
    cx.bAh = (const unsigned short*)(wsc + H0P_B + pa*SLOT_B);
    cx.bAl = (const unsigned short*)(wsc + H0P_B + pa*SLOT_B + PL_B);
    cx.bBh = (const unsigned short*)(wsc + H1P_B + pb2*SLOT_B);
    cx.bBl = (const unsigned short*)(wsc + H1P_B + pb2*SLOT_B + PL_B);
    cx.oHh = (unsigned short*)(wsc + H1P_B + pa*SLOT_B);
    cx.oHl = (unsigned short*)(wsc + H1P_B + pa*SLOT_B + PL_B);
    cx.wih = wih1; cx.whh = whh1; cx.bsum = alw + DBS1;
    cx.cbuf = (float*)(wsc + C1_B);
  }
  return true;
}

/* ---------- SLOW step kernel (R19) ---------- */
__global__ __launch_bounds__(256) void step_kernel_slow(
  const float* __restrict__ obs, const int* __restrict__ lastAct,
  const float* __restrict__ reward, const float* __restrict__ wenc,
  const float* __restrict__ wih0, const float* __restrict__ whh0,
  const float* __restrict__ wih1, const float* __restrict__ whh1,
  float* __restrict__ ws, float* __restrict__ alw,
  float* __restrict__ out, int t)
{
  __shared__ unsigned short smem_u[18432];
  const int bid = blockIdx.x;
  const int tid = threadIdx.x;
  float* nd = (float*)((char*)ws + OFF_ND_B);
  char* wsc = (char*)ws;

  if (bid < 264){
    LstmCtx cx;
    if (!lstm_ctx(wsc, alw, bid, t, wih0, whh0, wih1, whh1, cx)) return;
    lstm_mfma_slow(smem_u, cx.j16, cx.nb, cx.step, cx.bAh, cx.bAl, cx.bBh, cx.bBl,
                   cx.oHh, cx.oHl, cx.wih, cx.whh, cx.bsum, nd, cx.cbuf, tid);
  } else if (bid < 328){
    const int te = t + 2;
    if (te < 0 || te > 255) return;
    enc_body((float*)smem_u, obs, wenc, alw, wsc, te, bid-264, tid);
  } else if (bid == 328){
    const int te = t + 2;
    if (te < 0 || te > 255) return;
    extras_body(wsc, reward, lastAct, te, tid);
  } else {
    const int s = t - 2;
    if (s < 0 || s > 255) return;
    head_body(wsc, alw, out, s, tid);
  }
}

/* ---------- FAST step kernel (pre-converted row-major weights) ---------- */
__global__ __launch_bounds__(256) void step_kernel_fast(
  const float* __restrict__ obs, const int* __restrict__ lastAct,
  const float* __restrict__ reward, const float* __restrict__ wenc,
  const float* __restrict__ wih0, const float* __restrict__ whh0,
  const float* __restrict__ wih1, const float* __restrict__ whh1,
  float* __restrict__ ws, float* __restrict__ alw,
  float* __restrict__ out, int t)
{
  __shared__ float smemf[8224];
  const int bid = blockIdx.x;
  const int tid = threadIdx.x;
  float* nd = (float*)((char*)ws + OFF_ND_B);
  char* wsc = (char*)ws;

  if (bid < 264){
    LstmCtx cx;
    if (!lstm_ctx(wsc, alw, bid, t, wih0, whh0, wih1, whh1, cx)) return;
    const unsigned short* wpreL =
        (const unsigned short*)(wsc + WPRE_B) + (size_t)cx.layer*LSTR_S;
    lstm_mfma_fast(smemf, cx.j16, cx.nb, cx.step, wpreL,
                   cx.bAh, cx.bAl, cx.bBh, cx.bBl,
                   cx.oHh, cx.oHl, cx.bsum, nd, cx.cbuf, tid);
  } else if (bid < 328){
    const int te = t + 2;
    if (te < 0 || te > 255) return;
    enc_body(smemf, obs, wenc, alw, wsc, te, bid-264, tid);
  } else if (bid == 328){
    const int te = t + 2;
    if (te < 0 || te > 255) return;
    extras_body(wsc, reward, lastAct, te, tid);
  } else {
    const int s = t - 2;
    if (s < 0 || s > 255) return;
    head_body(wsc, alw, out, s, tid);
  }
}

__global__ void finalize_kernel(const float* __restrict__ ws, float* __restrict__ out){
  int i = blockIdx.x*256 + threadIdx.x;
  if (i >= 2*HB) return;
  const char* wsc = (const char*)ws;
  const int l = i / HB;
  const int r = i % HB;
  const int bq = r / HDIM;
  const int j  = r % HDIM;
  const unsigned short* hh = (const unsigned short*)(wsc + (l==0?H0P_B:H1P_B) + 1*SLOT_B);
  const unsigned short* hl = hh + PL_B/2;
  const float* cf = (const float*)(wsc + (l==0?C0_B:C1_B));
  out[OUT_H + i] = bf2f(hh[(size_t)bq*PK + j]) + bf2f(hl[(size_t)bq*PK + j]);
  out[OUT_C + i] = cf[(size_t)j*BATCH + bq];
}

extern "C" void kernel_launch(void* const* d_in, const int* in_sizes, int n_in,
                              void* d_out, int out_size, void* d_ws, size_t ws_size,
                              hipStream_t stream) {
  const float* obs     = (const float*)d_in[0];
  const int*   lastAct = (const int*)  d_in[1];
  const float* reward  = (const float*)d_in[2];
  const void*  term    =               d_in[3];
  const float* Wenc    = (const float*)d_in[4];
  const float* benc    = (const float*)d_in[5];
  const float* wih0    = (const float*)d_in[6];
  const float* whh0    = (const float*)d_in[7];
  const float* bih0    = (const float*)d_in[8];
  const float* bhh0    = (const float*)d_in[9];
  const float* wih1    = (const float*)d_in[10];
  const float* whh1    = (const float*)d_in[11];
  const float* bih1    = (const float*)d_in[12];
  const float* bhh1    = (const float*)d_in[13];
  const float* Wpol    = (const float*)d_in[14];
  const float* bpol    = (const float*)d_in[15];
  const float* Wbase   = (const float*)d_in[16];
  const float* bbase   = (const float*)d_in[17];
  float*  ws   = (float*)d_ws;
  int*    flag = (int*)((char*)d_ws + OFF_FLAG_B);
  float*  alw  = (float*)((char*)d_ws + OFF_ALW_B);
  float*  out  = (float*)d_out;

  {
    const int nz = (WS_END_B - XP_B)/4;
    zero_kernel<<<(nz+255)/256, 256, 0, stream>>>(ws + XP_B/4, nz);
  }
  detect_term_kernel<<<1, 256, 0, stream>>>(term, flag);
  nd_kernel<<<(TSTEPS*BATCH+255)/256, 256, 0, stream>>>(term, flag, (float*)((char*)d_ws + OFF_ND_B));
  prep_small_kernel<<<(DALW_N+255)/256, 256, 0, stream>>>(alw,
      bih0, bhh0, bih1, bhh1, benc, Wpol, bpol, Wbase, bbase);

  const bool fast = (ws_size >= (size_t)NEED_FAST_B);
  if (fast){
    prep_w_kernel<<<1122, 256, 0, stream>>>(wih0, whh0, wih1, whh1,
        (unsigned short*)((char*)d_ws + WPRE_B));
    for (int t = -2; t <= 257; ++t)
      step_kernel_fast<<<330, 256, 0, stream>>>(
        obs, lastAct, reward, Wenc, wih0, whh0, wih1, whh1, ws, alw, out, t);
  } else {
    for (int t = -2; t <= 257; ++t)
      step_kernel_slow<<<330, 256, 0, stream>>>(
        obs, lastAct, reward, Wenc, wih0, whh0, wih1, whh1, ws, alw, out, t);
  }
  finalize_kernel<<<(2*HB+255)/256, 256, 0, stream>>>(ws, out);
}